// Round 1
// baseline (346.030 us; speedup 1.0000x reference)
//
#include <hip/hip_runtime.h>

#define TH  0.3f
#define DEC 0.2f

// LDS layout (float offsets)
#define OFF_X    0        // 38*38 = 1444 (x, zero-padded border)
#define OFF_W1   1444     // 270
#define OFF_B1   1714     // 30
#define OFF_W2   1744     // 2700
#define OFF_B2   4444     // 30
#define OFF_LIF  4474     // 4 (lw0,lw1,lw2,lb)
#define OFF_S    4480     // 10*20*20 = 4000 (pooled layer-1 output, padded); reused as h1 in epilogue
#define OFF_C2   8480     // 10*18*18*4 = 12960 (c2_mem, float4 per pixel)
#define SMEM_N   21440    // 85,760 bytes

__device__ __forceinline__ float spikef(float v) { return v > TH ? 1.f : 0.f; }

__device__ __forceinline__ void layer2_cell(float* sm, int cell,
                                            float lw0, float lw1, float lw2, float lb,
                                            float* h1acc)
{
    int oc  = cell / 81;
    int rem = cell - oc * 81;
    int hh  = rem / 9;
    int ww  = rem - hh * 9;
    int y0 = 2 * hh, x0 = 2 * ww;

    float acc[12]; // [pix][k]
    float b20 = 4.f * sm[OFF_B2 + oc];
    float b21 = 4.f * sm[OFF_B2 + 10 + oc];
    float b22 = 4.f * sm[OFF_B2 + 20 + oc];
    acc[0] = acc[3] = acc[6] = acc[9]  = b20;
    acc[1] = acc[4] = acc[7] = acc[10] = b21;
    acc[2] = acc[5] = acc[8] = acc[11] = b22;

    const float* srow = sm + OFF_S + y0 * 20 + x0;
    for (int ic = 0; ic < 10; ++ic) {
        float sv[16];
        #pragma unroll
        for (int r = 0; r < 4; ++r)
            #pragma unroll
            for (int c = 0; c < 4; ++c)
                sv[r * 4 + c] = srow[ic * 400 + r * 20 + c];
        #pragma unroll
        for (int k = 0; k < 3; ++k) {
            const float* wp = sm + OFF_W2 + ((k * 10 + oc) * 10 + ic) * 9;
            #pragma unroll
            for (int r = 0; r < 3; ++r)
                #pragma unroll
                for (int c = 0; c < 3; ++c) {
                    float wv = wp[r * 3 + c];
                    acc[0 * 3 + k] = fmaf(sv[r * 4 + c],           wv, acc[0 * 3 + k]);
                    acc[1 * 3 + k] = fmaf(sv[r * 4 + c + 1],       wv, acc[1 * 3 + k]);
                    acc[2 * 3 + k] = fmaf(sv[(r + 1) * 4 + c],     wv, acc[2 * 3 + k]);
                    acc[3 * 3 + k] = fmaf(sv[(r + 1) * 4 + c + 1], wv, acc[3 * 3 + k]);
                }
        }
    }
    #pragma unroll
    for (int pix = 0; pix < 4; ++pix) {
        float4* mp = reinterpret_cast<float4*>(sm + OFF_C2) + cell * 4 + pix;
        float4 m = *mp;  // zeros at t=0 (smem zero-initialized)
        float inner = m.x * lw0 + m.y * lw1 + m.z * lw2 + lb;
        float4 n;
        n.x = (m.x > TH ? 0.f : m.x * DEC) + acc[pix * 3 + 0];
        n.y = (m.y > TH ? 0.f : m.y * DEC) + acc[pix * 3 + 1];
        n.z = (m.z > TH ? 0.f : m.z * DEC) + acc[pix * 3 + 2];
        n.w = (m.w > TH ? 0.f : m.w * DEC) + inner;
        *mp = n;
        h1acc[0] += spikef(n.x) * 0.25f;
        h1acc[1] += spikef(n.y) * 0.25f;
        h1acc[2] += spikef(n.z) * 0.25f;
        h1acc[3] += spikef(n.w) * 0.25f;
    }
}

__global__ __launch_bounds__(512)
void scnn_kernel(const float* __restrict__ x,
                 const float* __restrict__ w1, const float* __restrict__ b1,
                 const float* __restrict__ w2, const float* __restrict__ b2,
                 const float* __restrict__ lif_w, const float* __restrict__ lif_b,
                 const float* __restrict__ fc_w, const float* __restrict__ fc_b,
                 const float* __restrict__ task_w, const float* __restrict__ task_b,
                 const int* __restrict__ tw_ptr,
                 float* __restrict__ out, float* __restrict__ c1mem)
{
    __shared__ float sm[SMEM_N];
    const int tid = threadIdx.x;
    const int b   = blockIdx.x;
    const int T   = tw_ptr[0];

    for (int i = tid; i < SMEM_N; i += 512) sm[i] = 0.f;
    __syncthreads();

    for (int i = tid; i < 1296; i += 512) {
        int h = i / 36, w = i - h * 36;
        sm[OFF_X + (h + 1) * 38 + (w + 1)] = x[b * 1296 + i];
    }
    if (tid < 270) sm[OFF_W1 + tid] = w1[tid];
    if (tid < 30)  sm[OFF_B1 + tid] = b1[tid];
    for (int i = tid; i < 2700; i += 512) sm[OFF_W2 + i] = w2[i];
    if (tid < 30)  sm[OFF_B2 + tid] = b2[tid];
    if (tid < 3)   sm[OFF_LIF + tid] = lif_w[tid];
    if (tid == 0)  sm[OFF_LIF + 3] = lif_b[0];
    __syncthreads();

    const float lw0 = sm[OFF_LIF + 0], lw1 = sm[OFF_LIF + 1],
                lw2 = sm[OFF_LIF + 2], lb  = sm[OFF_LIF + 3];

    float h1a[4] = {0.f, 0.f, 0.f, 0.f};
    float h1b[4] = {0.f, 0.f, 0.f, 0.f};

    // c1_mem layout: [b][cell(3240)][pix(4)] float4 (64B per cell)
    float4* c1 = reinterpret_cast<float4*>(c1mem) + (size_t)b * 3240 * 4;

    for (int t = 0; t < T; ++t) {
        // ---- layer 1: conv drives (from LDS x) + LIF update + pooled sum into s ----
        for (int cell = tid; cell < 3240; cell += 512) {
            int oc  = cell / 324;
            int rem = cell - oc * 324;
            int hh  = rem / 18;
            int ww  = rem - hh * 18;

            float wr[27];
            #pragma unroll
            for (int k = 0; k < 3; ++k)
                #pragma unroll
                for (int j = 0; j < 9; ++j)
                    wr[k * 9 + j] = sm[OFF_W1 + (k * 10 + oc) * 9 + j];
            float bb0 = sm[OFF_B1 + oc];
            float bb1 = sm[OFF_B1 + 10 + oc];
            float bb2 = sm[OFF_B1 + 20 + oc];

            float4* cptr = c1 + (size_t)cell * 4;
            float sum_spk = 0.f;
            #pragma unroll
            for (int pix = 0; pix < 4; ++pix) {
                int y  = 2 * hh + (pix >> 1);
                int xx = 2 * ww + (pix & 1);
                float d0 = bb0, d1 = bb1, d2 = bb2;
                #pragma unroll
                for (int r = 0; r < 3; ++r)
                    #pragma unroll
                    for (int c = 0; c < 3; ++c) {
                        float xv = sm[OFF_X + (y + r) * 38 + (xx + c)];
                        d0 = fmaf(xv, wr[0 + r * 3 + c], d0);
                        d1 = fmaf(xv, wr[9 + r * 3 + c], d1);
                        d2 = fmaf(xv, wr[18 + r * 3 + c], d2);
                    }
                float4 m;
                if (t == 0) m = make_float4(0.f, 0.f, 0.f, 0.f);
                else        m = cptr[pix];
                float inner = m.x * lw0 + m.y * lw1 + m.z * lw2 + lb;
                float4 n;
                n.x = (m.x > TH ? 0.f : m.x * DEC) + d0;
                n.y = (m.y > TH ? 0.f : m.y * DEC) + d1;
                n.z = (m.z > TH ? 0.f : m.z * DEC) + d2;
                n.w = (m.w > TH ? 0.f : m.w * DEC) + inner;
                if (t + 1 < T) cptr[pix] = n;   // last step's state never read again
                sum_spk += spikef(n.x) + spikef(n.y) + spikef(n.z) + spikef(n.w);
            }
            sm[OFF_S + oc * 400 + (hh + 1) * 20 + (ww + 1)] = sum_spk * 0.25f;
        }
        __syncthreads();

        // ---- layer 2: conv over s (LDS) + LIF (c2_mem in LDS) + pool into h1 regs ----
        layer2_cell(sm, tid, lw0, lw1, lw2, lb, h1a);
        if (tid + 512 < 810) layer2_cell(sm, tid + 512, lw0, lw1, lw2, lb, h1b);
        __syncthreads();
    }

    // ---- epilogue: h1 -> LDS, FC(50x3240), task heads (3x10x50) ----
    {
        #pragma unroll
        for (int k = 0; k < 4; ++k) sm[OFF_S + tid * 4 + k] = h1a[k];
        if (tid + 512 < 810) {
            #pragma unroll
            for (int k = 0; k < 4; ++k) sm[OFF_S + (tid + 512) * 4 + k] = h1b[k];
        }
    }
    __syncthreads();

    float invT = 1.f / (float)T;
    int f = tid >> 3, g = tid & 7;
    if (f < 50) {
        const float* wrow = fc_w + f * 3240;
        float p0 = 0.f, p1 = 0.f;
        for (int j = g; j < 3240; j += 16) {
            p0 = fmaf(sm[OFF_S + j], wrow[j], p0);
            if (j + 8 < 3240) p1 = fmaf(sm[OFF_S + j + 8], wrow[j + 8], p1);
        }
        float p = p0 + p1;
        p += __shfl_xor(p, 1);
        p += __shfl_xor(p, 2);
        p += __shfl_xor(p, 4);
        if (g == 0) sm[OFF_X + f] = p * invT + fc_b[f];
    }
    __syncthreads();

    if (tid < 30) {
        float acc = task_b[tid];
        const float* twp = task_w + tid * 50;
        for (int j = 0; j < 50; ++j) acc = fmaf(sm[OFF_X + j], twp[j], acc);
        out[b * 30 + tid] = acc;
    }
}

extern "C" void kernel_launch(void* const* d_in, const int* in_sizes, int n_in,
                              void* d_out, int out_size, void* d_ws, size_t ws_size,
                              hipStream_t stream) {
    const float* x      = (const float*)d_in[0];
    const float* w1     = (const float*)d_in[1];
    const float* b1     = (const float*)d_in[2];
    const float* w2     = (const float*)d_in[3];
    const float* b2     = (const float*)d_in[4];
    const float* lif_w  = (const float*)d_in[5];
    const float* lif_b  = (const float*)d_in[6];
    const float* fc_w   = (const float*)d_in[7];
    const float* fc_b   = (const float*)d_in[8];
    const float* task_w = (const float*)d_in[9];
    const float* task_b = (const float*)d_in[10];
    const int*   tw     = (const int*)d_in[11];

    int B = in_sizes[0] / 1296;  // x is (B,1,36,36)

    scnn_kernel<<<B, 512, 0, stream>>>(x, w1, b1, w2, b2, lif_w, lif_b,
                                       fc_w, fc_b, task_w, task_b, tw,
                                       (float*)d_out, (float*)d_ws);
}